// Round 1
// baseline (514.611 us; speedup 1.0000x reference)
//
#include <hip/hip_runtime.h>

// ---------------------------------------------------------------------------
// Fused 2.5D window attention, one 256-thread block per window (B = 8192).
// Round 3: kill the LDS-transpose critical path.
//   - Q^T / K^T computed by MFMA operand swap; sigma-permuted k-index makes
//     ALL of Q, K, V, P fragment hand-offs lane-local (zero LDS round trips).
//   - softmax denominator: in-lane sum + 2 shfl_xor (was 64 shfls).
//   - LDS = XS staging [64][128] bf16 (rows 49..63 zeroed) overlaid by
//     OS [49][136] for the cross-wave out-projection. 16384 B total.
//   - barriers 4 -> 3, scalar ds_writes ~180 -> ~26 per lane.
// ---------------------------------------------------------------------------

typedef __bf16 bf16x8 __attribute__((ext_vector_type(8)));
typedef float f32x4 __attribute__((ext_vector_type(4)));
typedef unsigned short u16x8 __attribute__((ext_vector_type(8)));

__device__ __forceinline__ unsigned short bf16c(float f) {
  return __builtin_bit_cast(unsigned short, (__bf16)f);
}
__device__ __forceinline__ bf16x8 ld8(const unsigned short* p) {  // 16B aligned
  return __builtin_bit_cast(bf16x8, *(const u16x8*)p);
}

// ---------------------------------------------------------------------------
__global__ void prep(const float* __restrict__ wq, const float* __restrict__ wo,
                     const float* __restrict__ bt,
                     unsigned short* __restrict__ wTq,
                     unsigned short* __restrict__ wTo,
                     float* __restrict__ bias2) {
  int t = blockIdx.x * 256 + threadIdx.x;
  if (t < 49152) {                       // wTq[n*128+k] = bf16(wq[k*384+n]), SCALE folded into q cols
    int n = t >> 7, k = t & 127;
    float v = wq[k * 384 + n];
    if (n < 128) v *= 0.17677669529663689f;   // DIM_HEAD^-0.5
    wTq[t] = bf16c(v);
  } else if (t < 65536) {                // wTo[n*128+k] = bf16(wo[k*128+n])
    int i = t - 49152;
    int n = i >> 7, k = i & 127;
    wTo[i] = bf16c(wo[k * 128 + n]);
  } else {                               // bias2T[h][it][c][jt][q][r] : S^T layout
    int i = t - 65536;                   // row j = jt*16+q*4+r (key), col i = it*16+c (query)
    int r = i & 3, q = (i >> 2) & 3, jt = (i >> 4) & 3;
    int c = (i >> 6) & 15, it = (i >> 10) & 3, h = (i >> 12) & 3;
    int j = jt * 16 + q * 4 + r;
    int ii = it * 16 + c;
    int iq = ii < 49 ? ii : 48;          // dup for padding queries (finite, unused)
    float v = -1e30f;                    // masks key rows j >= 49
    if (j < 49) {
      int ri = iq / 7 - j / 7 + 6;
      int rj = iq % 7 - j % 7 + 6;
      v = bt[(ri * 13 + rj) * 4 + h];
    }
    bias2[i] = v;
  }
}

// ---------------------------------------------------------------------------
__global__ __launch_bounds__(256, 4) void attn_fused(
    const float* __restrict__ x,
    const unsigned short* __restrict__ wTq,
    const unsigned short* __restrict__ wTo,
    const f32x4* __restrict__ bias2,
    float* __restrict__ out) {
  // phase A: XS bf16 [64][128] granule-swizzled (rows 49..63 zero)  = 8192 ush
  // phase B: OS bf16 [49][136] (overlays XS after B2)               = 6664 ush
  __shared__ __align__(16) unsigned short lds[8192];

  const int tid = threadIdx.x;
  const int wave = tid >> 6;
  const int lane = tid & 63;
  const int c16 = lane & 15;
  const int quad = lane >> 4;
  const int q4 = quad * 4;
  const int h = wave;                 // wave == head
  const f32x4 zero4 = {0.f, 0.f, 0.f, 0.f};

  const float* xb = x + (size_t)blockIdx.x * 6272;

  // ---- stage x rows 0..48 -> bf16 swizzled; rows 49..63 zeroed ------------
  for (int c = tid; c < 1024; c += 256) {          // 64 rows x 16 chunks, 4 iters
    int row = c >> 4, c8 = c & 15;
    bf16x8 v;
    if (row < 49) {
      const float4* p = (const float4*)(xb + row * 128 + c8 * 8);
      float4 f0 = p[0], f1 = p[1];
      v[0] = (__bf16)f0.x; v[1] = (__bf16)f0.y; v[2] = (__bf16)f0.z; v[3] = (__bf16)f0.w;
      v[4] = (__bf16)f1.x; v[5] = (__bf16)f1.y; v[6] = (__bf16)f1.z; v[7] = (__bf16)f1.w;
    } else {
#pragma unroll
      for (int e = 0; e < 8; ++e) v[e] = (__bf16)0.f;
    }
    *(u16x8*)&lds[row * 128 + ((c8 ^ (row & 7)) << 3)] = __builtin_bit_cast(u16x8, v);
  }
  __syncthreads();  // B1: xs staged

  // ---- QKV: Q^T, K^T via operand swap; V normal. All results -> regs ------
  // token tiles {0,16,32,48}; rows 49..63 are zeros (harmless, masked by bias)
  const u16x8* wq8 = (const u16x8*)wTq;
  bf16x8 bq[4];        // B-frag of Q^T per query tile it: Q[16it+c16][sigma_d(q,e)]
  bf16x8 ak[4];        // A-frag of K  per key tile jt:   K[16jt+c16][sigma_d(q,e)]
  bf16x8 bv[2][2];     // B-frag of V  per (kk, dh-tile): V[sigma_t(kk,q,e)][16j2+c16]
#pragma unroll
  for (int p = 0; p < 3; ++p) {
    f32x4 acc[4][2];
#pragma unroll
    for (int m = 0; m < 4; ++m) { acc[m][0] = zero4; acc[m][1] = zero4; }
#pragma unroll
    for (int kk = 0; kk < 4; ++kk) {
      bf16x8 a[4];
#pragma unroll
      for (int m = 0; m < 4; ++m)       // (16m+c16)&7 == c16&7
        a[m] = ld8(&lds[(16 * m + c16) * 128 + ((((kk << 2) | quad) ^ (c16 & 7)) << 3)]);
      bf16x8 b[2];
#pragma unroll
      for (int j = 0; j < 2; ++j)
        b[j] = __builtin_bit_cast(bf16x8,
               wq8[(p * 128 + h * 32 + j * 16 + c16) * 16 + (kk << 2) + quad]);
#pragma unroll
      for (int j = 0; j < 2; ++j)
#pragma unroll
        for (int m = 0; m < 4; ++m)
          acc[m][j] = (p < 2)
            ? __builtin_amdgcn_mfma_f32_16x16x32_bf16(b[j], a[m], acc[m][j], 0, 0, 0)
            : __builtin_amdgcn_mfma_f32_16x16x32_bf16(a[m], b[j], acc[m][j], 0, 0, 0);
    }
    if (p == 0) {        // Q^T tiles: row dim=16*j2+q4+r, col token=16m+c16
#pragma unroll
      for (int it = 0; it < 4; ++it)
#pragma unroll
        for (int e = 0; e < 8; ++e)
          bq[it][e] = (__bf16)acc[it][e >> 2][e & 3];
    } else if (p == 1) { // K^T tiles, same lane-local mapping
#pragma unroll
      for (int jt = 0; jt < 4; ++jt)
#pragma unroll
        for (int e = 0; e < 8; ++e)
          ak[jt][e] = (__bf16)acc[jt][e >> 2][e & 3];
    } else {             // V normal: row token=16m+q4+r, col dh=16*j2+c16
#pragma unroll
      for (int kk = 0; kk < 2; ++kk)
#pragma unroll
        for (int j2 = 0; j2 < 2; ++j2)
#pragma unroll
          for (int e = 0; e < 8; ++e)
            bv[kk][j2][e] = (__bf16)acc[2 * kk + (e >> 2)][j2][e & 3];
    }
  }
  __syncthreads();  // B2: XS dead for all waves -> OS overlay writable

  // ---- per query tile: S^T (bias in MFMA C), lane-local softmax, PV, OS ---
#pragma unroll
  for (int it = 0; it < 4; ++it) {
    f32x4 s[4];
#pragma unroll
    for (int jt = 0; jt < 4; ++jt) {
      f32x4 b4 = bias2[((h * 4 + it) * 16 + c16) * 16 + jt * 4 + quad];
      s[jt] = __builtin_amdgcn_mfma_f32_16x16x32_bf16(ak[jt], bq[it], b4, 0, 0, 0);
    }
    float e[4][4];
#pragma unroll
    for (int jt = 0; jt < 4; ++jt)
#pragma unroll
      for (int r = 0; r < 4; ++r)
        e[jt][r] = __expf(s[jt][r]);
    float rs = ((e[0][0] + e[0][1]) + (e[0][2] + e[0][3]))
             + ((e[1][0] + e[1][1]) + (e[1][2] + e[1][3]))
             + ((e[2][0] + e[2][1]) + (e[2][2] + e[2][3]))
             + ((e[3][0] + e[3][1]) + (e[3][2] + e[3][3]));
    rs += __shfl_xor(rs, 16);
    rs += __shfl_xor(rs, 32);
    float rinv = __builtin_amdgcn_rcpf(rs);
    bf16x8 pa[2];      // A-frag of normalized P: P[16it+c16][sigma_t(kk,q,e)]
#pragma unroll
    for (int kk = 0; kk < 2; ++kk)
#pragma unroll
      for (int ee = 0; ee < 8; ++ee)
        pa[kk][ee] = (__bf16)(e[2 * kk + (ee >> 2)][ee & 3] * rinv);
    f32x4 o0 = zero4, o1 = zero4;
#pragma unroll
    for (int kk = 0; kk < 2; ++kk) {
      o0 = __builtin_amdgcn_mfma_f32_16x16x32_bf16(pa[kk], bv[kk][0], o0, 0, 0, 0);
      o1 = __builtin_amdgcn_mfma_f32_16x16x32_bf16(pa[kk], bv[kk][1], o1, 0, 0, 0);
    }
#pragma unroll
    for (int r = 0; r < 4; ++r) {
      int row = 16 * it + q4 + r;       // queries; only rows < 49 are real
      if (row < 49) {
        lds[row * 136 + h * 32 + c16]      = bf16c(o0[r]);
        lds[row * 136 + h * 32 + 16 + c16] = bf16c(o1[r]);
      }
    }
  }
  __syncthreads();  // B3: OS ready (cross-wave read next)

  // ---- out = O @ w_out (row tiles {0,16,32,33}: all reads/writes real) ----
  const u16x8* wo8 = (const u16x8*)wTo;
  const int MOFF2[4] = {0, 16, 32, 33};
  f32x4 oc[4][2];
#pragma unroll
  for (int m = 0; m < 4; ++m) { oc[m][0] = zero4; oc[m][1] = zero4; }
#pragma unroll
  for (int kk = 0; kk < 4; ++kk) {
    bf16x8 a2[4];
#pragma unroll
    for (int m = 0; m < 4; ++m)
      a2[m] = ld8(&lds[(MOFF2[m] + c16) * 136 + kk * 32 + quad * 8]);
#pragma unroll
    for (int j = 0; j < 2; ++j) {
      bf16x8 b2 = __builtin_bit_cast(bf16x8,
                  wo8[((2 * wave + j) * 16 + c16) * 16 + (kk << 2) + quad]);
#pragma unroll
      for (int m = 0; m < 4; ++m)
        oc[m][j] = __builtin_amdgcn_mfma_f32_16x16x32_bf16(a2[m], b2, oc[m][j], 0, 0, 0);
    }
  }

  float* op = out + (size_t)blockIdx.x * 6272;
#pragma unroll
  for (int m = 0; m < 4; ++m)
#pragma unroll
    for (int r = 0; r < 4; ++r) {
      int row = MOFF2[m] + q4 + r;      // 0..48 all valid; 33..47 dup-identical
#pragma unroll
      for (int j = 0; j < 2; ++j)
        op[row * 128 + (2 * wave + j) * 16 + c16] = oc[m][j][r];
    }
}

// ---------------------------------------------------------------------------
extern "C" void kernel_launch(void* const* d_in, const int* in_sizes, int n_in,
                              void* d_out, int out_size, void* d_ws, size_t ws_size,
                              hipStream_t stream) {
  const float* x = (const float*)d_in[0];
  const float* wq = (const float*)d_in[1];
  const float* wo = (const float*)d_in[2];
  const float* bt = (const float*)d_in[3];

  // workspace: wTq bf16 [384*128] | wTo bf16 [128*128] | bias2T f32 [16384]
  unsigned short* wTq = (unsigned short*)d_ws;
  unsigned short* wTo = wTq + 49152;
  float* bias2 = (float*)((char*)d_ws + 131072);

  prep<<<320, 256, 0, stream>>>(wq, wo, bt, wTq, wTo, bias2);
  attn_fused<<<8192, 256, 0, stream>>>(x, wTq, wTo, (const f32x4*)bias2, (float*)d_out);
}

// Round 2
// 497.605 us; speedup vs baseline: 1.0342x; 1.0342x over previous
//
#include <hip/hip_runtime.h>

// ---------------------------------------------------------------------------
// Fused 2.5D window attention, one 256-thread block per window (B = 8192).
// Round 4: fix the round-3 register spill.
//   - launch_bounds (256,3): VGPR cap 170 (was 128 -> ~12 regs spilled to
//     scratch = +100MB HBM writes +55MB reads, +58us)
//   - V pass j2-split: live f32 acc 32 -> 16 regs in the peak-pressure phase
//   - dup output rows 33..47 stored once (m=3 tile stores only row 48)
//   - algorithm unchanged from round 3: sigma-permuted lane-local Q/K/V/P
//     fragment hand-offs, zero LDS transposes, 2-shfl softmax.
// ---------------------------------------------------------------------------

typedef __bf16 bf16x8 __attribute__((ext_vector_type(8)));
typedef float f32x4 __attribute__((ext_vector_type(4)));
typedef unsigned short u16x8 __attribute__((ext_vector_type(8)));

__device__ __forceinline__ unsigned short bf16c(float f) {
  return __builtin_bit_cast(unsigned short, (__bf16)f);
}
__device__ __forceinline__ bf16x8 ld8(const unsigned short* p) {  // 16B aligned
  return __builtin_bit_cast(bf16x8, *(const u16x8*)p);
}

// ---------------------------------------------------------------------------
__global__ void prep(const float* __restrict__ wq, const float* __restrict__ wo,
                     const float* __restrict__ bt,
                     unsigned short* __restrict__ wTq,
                     unsigned short* __restrict__ wTo,
                     float* __restrict__ bias2) {
  int t = blockIdx.x * 256 + threadIdx.x;
  if (t < 49152) {                       // wTq[n*128+k] = bf16(wq[k*384+n]), SCALE folded into q cols
    int n = t >> 7, k = t & 127;
    float v = wq[k * 384 + n];
    if (n < 128) v *= 0.17677669529663689f;   // DIM_HEAD^-0.5
    wTq[t] = bf16c(v);
  } else if (t < 65536) {                // wTo[n*128+k] = bf16(wo[k*128+n])
    int i = t - 49152;
    int n = i >> 7, k = i & 127;
    wTo[i] = bf16c(wo[k * 128 + n]);
  } else {                               // bias2T[h][it][c][jt][q][r] : S^T layout
    int i = t - 65536;                   // row j = jt*16+q*4+r (key), col i = it*16+c (query)
    int r = i & 3, q = (i >> 2) & 3, jt = (i >> 4) & 3;
    int c = (i >> 6) & 15, it = (i >> 10) & 3, h = (i >> 12) & 3;
    int j = jt * 16 + q * 4 + r;
    int ii = it * 16 + c;
    int iq = ii < 49 ? ii : 48;          // dup for padding queries (finite, unused)
    float v = -1e30f;                    // masks key rows j >= 49
    if (j < 49) {
      int ri = iq / 7 - j / 7 + 6;
      int rj = iq % 7 - j % 7 + 6;
      v = bt[(ri * 13 + rj) * 4 + h];
    }
    bias2[i] = v;
  }
}

// ---------------------------------------------------------------------------
__global__ __launch_bounds__(256, 3) void attn_fused(
    const float* __restrict__ x,
    const unsigned short* __restrict__ wTq,
    const unsigned short* __restrict__ wTo,
    const f32x4* __restrict__ bias2,
    float* __restrict__ out) {
  // phase A: XS bf16 [64][128] granule-swizzled (rows 49..63 zero)  = 8192 ush
  // phase B: OS bf16 [49][136] (overlays XS after B2)               = 6664 ush
  __shared__ __align__(16) unsigned short lds[8192];

  const int tid = threadIdx.x;
  const int wave = tid >> 6;
  const int lane = tid & 63;
  const int c16 = lane & 15;
  const int quad = lane >> 4;
  const int q4 = quad * 4;
  const int h = wave;                 // wave == head
  const f32x4 zero4 = {0.f, 0.f, 0.f, 0.f};

  const float* xb = x + (size_t)blockIdx.x * 6272;

  // ---- stage x rows 0..48 -> bf16 swizzled; rows 49..63 zeroed ------------
  for (int c = tid; c < 1024; c += 256) {          // 64 rows x 16 chunks, 4 iters
    int row = c >> 4, c8 = c & 15;
    bf16x8 v;
    if (row < 49) {
      const float4* p = (const float4*)(xb + row * 128 + c8 * 8);
      float4 f0 = p[0], f1 = p[1];
      v[0] = (__bf16)f0.x; v[1] = (__bf16)f0.y; v[2] = (__bf16)f0.z; v[3] = (__bf16)f0.w;
      v[4] = (__bf16)f1.x; v[5] = (__bf16)f1.y; v[6] = (__bf16)f1.z; v[7] = (__bf16)f1.w;
    } else {
#pragma unroll
      for (int e = 0; e < 8; ++e) v[e] = (__bf16)0.f;
    }
    *(u16x8*)&lds[row * 128 + ((c8 ^ (row & 7)) << 3)] = __builtin_bit_cast(u16x8, v);
  }
  __syncthreads();  // B1: xs staged

  // ---- QKV: Q^T, K^T via operand swap; V normal. All results -> regs ------
  // token tiles {0,16,32,48}; rows 49..63 are zeros (harmless, masked by bias)
  const u16x8* wq8 = (const u16x8*)wTq;
  bf16x8 bq[4];        // B-frag of Q^T per query tile it: Q[16it+c16][sigma_d(q,e)]
  bf16x8 ak[4];        // A-frag of K  per key tile jt:   K[16jt+c16][sigma_d(q,e)]
  bf16x8 bv[2][2];     // B-frag of V  per (kk, dh-tile): V[sigma_t(kk,q,e)][16j2+c16]

#pragma unroll
  for (int p = 0; p < 2; ++p) {          // p=0: Q^T, p=1: K^T (operand-swapped)
    f32x4 acc[4][2];
#pragma unroll
    for (int m = 0; m < 4; ++m) { acc[m][0] = zero4; acc[m][1] = zero4; }
#pragma unroll
    for (int kk = 0; kk < 4; ++kk) {
      bf16x8 a[4];
#pragma unroll
      for (int m = 0; m < 4; ++m)       // (16m+c16)&7 == c16&7
        a[m] = ld8(&lds[(16 * m + c16) * 128 + ((((kk << 2) | quad) ^ (c16 & 7)) << 3)]);
#pragma unroll
      for (int j = 0; j < 2; ++j) {
        bf16x8 b = __builtin_bit_cast(bf16x8,
                   wq8[(p * 128 + h * 32 + j * 16 + c16) * 16 + (kk << 2) + quad]);
#pragma unroll
        for (int m = 0; m < 4; ++m)
          acc[m][j] = __builtin_amdgcn_mfma_f32_16x16x32_bf16(b, a[m], acc[m][j], 0, 0, 0);
      }
    }
    if (p == 0) {        // Q^T tiles: row dim=16*j+q4+r, col token=16it+c16
#pragma unroll
      for (int it = 0; it < 4; ++it)
#pragma unroll
        for (int e = 0; e < 8; ++e)
          bq[it][e] = (__bf16)acc[it][e >> 2][e & 3];
    } else {             // K^T tiles, same lane-local mapping
#pragma unroll
      for (int jt = 0; jt < 4; ++jt)
#pragma unroll
        for (int e = 0; e < 8; ++e)
          ak[jt][e] = (__bf16)acc[jt][e >> 2][e & 3];
    }
  }
  // V pass, normal orientation, j2-split (live acc 16 regs instead of 32)
#pragma unroll
  for (int j2 = 0; j2 < 2; ++j2) {
    f32x4 acc2[4];
#pragma unroll
    for (int m = 0; m < 4; ++m) acc2[m] = zero4;
#pragma unroll
    for (int kk = 0; kk < 4; ++kk) {
      bf16x8 b = __builtin_bit_cast(bf16x8,
                 wq8[(256 + h * 32 + j2 * 16 + c16) * 16 + (kk << 2) + quad]);
#pragma unroll
      for (int m = 0; m < 4; ++m) {
        bf16x8 a = ld8(&lds[(16 * m + c16) * 128 + ((((kk << 2) | quad) ^ (c16 & 7)) << 3)]);
        acc2[m] = __builtin_amdgcn_mfma_f32_16x16x32_bf16(a, b, acc2[m], 0, 0, 0);
      }
    }
    // V[row token=16m+q4+r][col dh=16j2+c16] -> bv[m>>1][j2][4*(m&1)+r]
#pragma unroll
    for (int m = 0; m < 4; ++m)
#pragma unroll
      for (int r = 0; r < 4; ++r)
        bv[m >> 1][j2][4 * (m & 1) + r] = (__bf16)acc2[m][r];
  }
  __syncthreads();  // B2: XS dead for all waves -> OS overlay writable

  // ---- per query tile: S^T (bias in MFMA C), lane-local softmax, PV, OS ---
#pragma unroll
  for (int it = 0; it < 4; ++it) {
    f32x4 s[4];
#pragma unroll
    for (int jt = 0; jt < 4; ++jt) {
      f32x4 b4 = bias2[((h * 4 + it) * 16 + c16) * 16 + jt * 4 + quad];
      s[jt] = __builtin_amdgcn_mfma_f32_16x16x32_bf16(ak[jt], bq[it], b4, 0, 0, 0);
    }
    float e[4][4];
#pragma unroll
    for (int jt = 0; jt < 4; ++jt)
#pragma unroll
      for (int r = 0; r < 4; ++r)
        e[jt][r] = __expf(s[jt][r]);
    float rs = ((e[0][0] + e[0][1]) + (e[0][2] + e[0][3]))
             + ((e[1][0] + e[1][1]) + (e[1][2] + e[1][3]))
             + ((e[2][0] + e[2][1]) + (e[2][2] + e[2][3]))
             + ((e[3][0] + e[3][1]) + (e[3][2] + e[3][3]));
    rs += __shfl_xor(rs, 16);
    rs += __shfl_xor(rs, 32);
    float rinv = __builtin_amdgcn_rcpf(rs);
    bf16x8 pa[2];      // A-frag of normalized P: P[16it+c16][sigma_t(kk,q,e)]
#pragma unroll
    for (int kk = 0; kk < 2; ++kk)
#pragma unroll
      for (int ee = 0; ee < 8; ++ee)
        pa[kk][ee] = (__bf16)(e[2 * kk + (ee >> 2)][ee & 3] * rinv);
    f32x4 o0 = zero4, o1 = zero4;
#pragma unroll
    for (int kk = 0; kk < 2; ++kk) {
      o0 = __builtin_amdgcn_mfma_f32_16x16x32_bf16(pa[kk], bv[kk][0], o0, 0, 0, 0);
      o1 = __builtin_amdgcn_mfma_f32_16x16x32_bf16(pa[kk], bv[kk][1], o1, 0, 0, 0);
    }
#pragma unroll
    for (int r = 0; r < 4; ++r) {
      int row = 16 * it + q4 + r;       // queries; only rows < 49 are real
      if (row < 49) {
        lds[row * 136 + h * 32 + c16]      = bf16c(o0[r]);
        lds[row * 136 + h * 32 + 16 + c16] = bf16c(o1[r]);
      }
    }
  }
  __syncthreads();  // B3: OS ready (cross-wave read next)

  // ---- out = O @ w_out (row tiles {0,16,32,33}) ---------------------------
  const u16x8* wo8 = (const u16x8*)wTo;
  const int MOFF2[4] = {0, 16, 32, 33};
  f32x4 oc[4][2];
#pragma unroll
  for (int m = 0; m < 4; ++m) { oc[m][0] = zero4; oc[m][1] = zero4; }
#pragma unroll
  for (int kk = 0; kk < 4; ++kk) {
    bf16x8 a2[4];
#pragma unroll
    for (int m = 0; m < 4; ++m)
      a2[m] = ld8(&lds[(MOFF2[m] + c16) * 136 + kk * 32 + quad * 8]);
#pragma unroll
    for (int j = 0; j < 2; ++j) {
      bf16x8 b2 = __builtin_bit_cast(bf16x8,
                  wo8[((2 * wave + j) * 16 + c16) * 16 + (kk << 2) + quad]);
#pragma unroll
      for (int m = 0; m < 4; ++m)
        oc[m][j] = __builtin_amdgcn_mfma_f32_16x16x32_bf16(a2[m], b2, oc[m][j], 0, 0, 0);
    }
  }

  float* op = out + (size_t)blockIdx.x * 6272;
#pragma unroll
  for (int m = 0; m < 4; ++m)
#pragma unroll
    for (int r = 0; r < 4; ++r) {
      int row = MOFF2[m] + q4 + r;      // 0..48 all valid
      // rows 33..47 of the m=3 tile duplicate m=2 rows: store only row 48
      if (m == 3 && row != 48) continue;
#pragma unroll
      for (int j = 0; j < 2; ++j)
        op[row * 128 + (2 * wave + j) * 16 + c16] = oc[m][j][r];
    }
}

// ---------------------------------------------------------------------------
extern "C" void kernel_launch(void* const* d_in, const int* in_sizes, int n_in,
                              void* d_out, int out_size, void* d_ws, size_t ws_size,
                              hipStream_t stream) {
  const float* x = (const float*)d_in[0];
  const float* wq = (const float*)d_in[1];
  const float* wo = (const float*)d_in[2];
  const float* bt = (const float*)d_in[3];

  // workspace: wTq bf16 [384*128] | wTo bf16 [128*128] | bias2T f32 [16384]
  unsigned short* wTq = (unsigned short*)d_ws;
  unsigned short* wTo = wTq + 49152;
  float* bias2 = (float*)((char*)d_ws + 131072);

  prep<<<320, 256, 0, stream>>>(wq, wo, bt, wTq, wTo, bias2);
  attn_fused<<<8192, 256, 0, stream>>>(x, wTq, wTo, (const f32x4*)bias2, (float*)d_out);
}